// Round 9
// baseline (480.350 us; speedup 1.0000x reference)
//
#include <hip/hip_runtime.h>
#include <hip/hip_bf16.h>

#define N_NODES   100000
#define FDIM      128
#define N_GRAPHS  64
#define N_CLASSES 32

#define NB        ((N_NODES + 255) / 256)     // 391 buckets of 256 nodes
#define EPB       8192                         // edges per block (hist/part)
#define SCAN_CHUNK 2048
#define CHS       ((size_t)N_NODES * 16)       // chunk stride in elements (chunk-major H)

typedef __attribute__((ext_vector_type(8))) short short8;
typedef __attribute__((ext_vector_type(4))) float f32x4;

__device__ __forceinline__ float bf2f(unsigned int u16) {
    unsigned int x = u16 << 16;
    return __builtin_bit_cast(float, x);
}
__device__ __forceinline__ unsigned short f2bf(float f) {
    unsigned int u = __builtin_bit_cast(unsigned int, f);
    unsigned int r = (u + 0x7fffu + ((u >> 16) & 1u)) >> 16;   // RNE
    return (unsigned short)r;
}

// ---------------- bucket histogram: hist[bucket * nblk + blk] ----------------
__global__ __launch_bounds__(256) void hist_kernel(const int* __restrict__ dst, int* __restrict__ hist,
                                                   int nE, int nblk) {
    __shared__ int h[NB];
    int t = threadIdx.x, blk = blockIdx.x;
    for (int i = t; i < NB; i += 256) h[i] = 0;
    __syncthreads();
    int base = blk * EPB;
    #pragma unroll
    for (int j = 0; j < EPB / 256; ++j) {
        int e = base + j * 256 + t;
        if (e < nE) atomicAdd(&h[dst[e] >> 8], 1);
    }
    __syncthreads();
    for (int i = t; i < NB; i += 256) hist[i * nblk + blk] = h[i];
}

// ---------------- generic two-level exclusive scan ----------------
__global__ __launch_bounds__(256) void scan_p1(const int* __restrict__ a, int* __restrict__ bsums, int n) {
    __shared__ int wsum[4];
    int b = blockIdx.x, t = threadIdx.x;
    int base = b * SCAN_CHUNK;
    int sum = 0;
    #pragma unroll
    for (int j = 0; j < SCAN_CHUNK / 256; ++j) {
        int idx = base + j * 256 + t;
        sum += (idx < n) ? a[idx] : 0;
    }
    #pragma unroll
    for (int off = 32; off; off >>= 1) sum += __shfl_down(sum, off, 64);
    int lane = t & 63, w = t >> 6;
    if (lane == 0) wsum[w] = sum;
    __syncthreads();
    if (t == 0) bsums[b] = wsum[0] + wsum[1] + wsum[2] + wsum[3];
}

__global__ __launch_bounds__(64) void scan_p2(int* __restrict__ bsums, int nb) {
    int t = threadIdx.x;
    int carry = 0;
    for (int base = 0; base < nb; base += 64) {
        int i = base + t;
        int v = (i < nb) ? bsums[i] : 0;
        int inc = v;
        #pragma unroll
        for (int off = 1; off < 64; off <<= 1) {
            int y = __shfl_up(inc, off, 64);
            if (t >= off) inc += y;
        }
        if (i < nb) bsums[i] = carry + inc - v;   // exclusive
        carry += __shfl(inc, 63, 64);
    }
}

__global__ __launch_bounds__(256) void scan_p3(const int* __restrict__ a, const int* __restrict__ bsums,
                                               int* __restrict__ out, int n) {
    __shared__ int wsum[4];
    int b = blockIdx.x, t = threadIdx.x;
    int lane = t & 63, w = t >> 6;
    int i0 = b * SCAN_CHUNK + t * 8;
    int v[8];
    int s = 0;
    #pragma unroll
    for (int j = 0; j < 8; ++j) {
        int idx = i0 + j;
        v[j] = (idx < n) ? a[idx] : 0;
        s += v[j];
    }
    int ps = s;
    #pragma unroll
    for (int off = 1; off < 64; off <<= 1) {
        int y = __shfl_up(ps, off, 64);
        if (lane >= off) ps += y;
    }
    if (lane == 63) wsum[w] = ps;
    __syncthreads();
    if (t == 0) {
        int acc = 0;
        #pragma unroll
        for (int i = 0; i < 4; ++i) { int tmp = wsum[i]; wsum[i] = acc; acc += tmp; }
    }
    __syncthreads();
    int run = (ps - s) + wsum[w] + bsums[b];
    #pragma unroll
    for (int j = 0; j < 8; ++j) {
        int idx = i0 + j;
        if (idx < n) out[idx] = run;
        run += v[j];
    }
}

// ---------------- partition edges into bucket-major record array ----------------
__global__ __launch_bounds__(256) void part_kernel(const int* __restrict__ src, const int* __restrict__ dst,
                                                   const int* __restrict__ offs,
                                                   unsigned long long* __restrict__ recs,
                                                   int nE, int nblk) {
    __shared__ int cur[NB];
    int t = threadIdx.x, blk = blockIdx.x;
    for (int i = t; i < NB; i += 256) cur[i] = offs[i * nblk + blk];
    __syncthreads();
    int base = blk * EPB;
    #pragma unroll
    for (int j = 0; j < EPB / 256; ++j) {
        int e = base + j * 256 + t;
        if (e < nE) {
            int s = src[e], d = dst[e];
            int pos = atomicAdd(&cur[d >> 8], 1);
            recs[pos] = (unsigned long long)(unsigned)s | ((unsigned long long)(unsigned)d << 32);
        }
    }
}

// ---------------- per-bucket CSR build WITH self-edges: row = [self | edges] ----------------
// slot space size = nE + N_NODES; row_ptr[node] = segBeg + node0 + edgePrefix + nodeLocal
__global__ __launch_bounds__(256) void csr_kernel(const unsigned long long* __restrict__ recs,
                                                  const int* __restrict__ offs,
                                                  int* __restrict__ row_ptr, int* __restrict__ esrc,
                                                  float* __restrict__ dinv, int nE, int nblk) {
    __shared__ int cnt[256];
    __shared__ int cur[256];
    __shared__ int wsum[4];
    int b = blockIdx.x, t = threadIdx.x;
    int node0 = b << 8;
    int segBeg = offs[b * nblk];
    int segEnd = (b + 1 < NB) ? offs[(b + 1) * nblk] : nE;
    cnt[t] = 0;
    __syncthreads();
    for (int e = segBeg + t; e < segEnd; e += 256) {
        int d = (int)(recs[e] >> 32);
        atomicAdd(&cnt[d - node0], 1);
    }
    __syncthreads();
    int c = cnt[t];
    int lane = t & 63, w = t >> 6;
    int ps = c;
    #pragma unroll
    for (int off = 1; off < 64; off <<= 1) {
        int y = __shfl_up(ps, off, 64);
        if (lane >= off) ps += y;
    }
    if (lane == 63) wsum[w] = ps;
    __syncthreads();
    if (t == 0) {
        int a = 0;
        #pragma unroll
        for (int i = 0; i < 4; ++i) { int tmp = wsum[i]; wsum[i] = a; a += tmp; }
    }
    __syncthreads();
    int node = node0 + t;
    int rbase = segBeg + node0 + (ps - c) + wsum[w] + t;   // includes self slots of prior nodes
    if (node < N_NODES) {
        row_ptr[node] = rbase;
        esrc[rbase] = node;            // self edge first
        dinv[node] = rsqrtf((float)c + 1.0f);
        cur[t] = rbase + 1;
    } else {
        cur[t] = 0;
    }
    if (b == NB - 1 && t == 0) row_ptr[N_NODES] = nE + N_NODES;
    __syncthreads();
    for (int e = segBeg + t; e < segEnd; e += 256) {
        unsigned long long r = recs[e];
        int d = (int)(r >> 32);
        int pos = atomicAdd(&cur[d - node0], 1);
        esrc[pos] = (int)(r & 0xffffffffu);
    }
}

// ---------------- W transpose + cast: WT[n][k] bf16 from W[k][n] f32 ----------------
__global__ __launch_bounds__(256) void wtrans(const float* __restrict__ W, unsigned short* __restrict__ WT) {
    int idx = blockIdx.x * 256 + threadIdx.x;
    int k = idx >> 7, n = idx & 127;
    WT[n * 128 + k] = f2bf(W[idx]);
}

// ---------------- MFMA GEMM: Hout (chunk-major bf16) = X @ W ----------------
// X: f32 row-major (IN_F32=1) or bf16 chunk-major (IN_F32=0); WT bf16 [n][k].
template<int IN_F32>
__global__ __launch_bounds__(256) void gemm_mfma(const void* __restrict__ Xv,
                                                 const unsigned short* __restrict__ WT,
                                                 unsigned short* __restrict__ H, int nrows) {
    __shared__ char lds[65536];
    char* xs  = lds;            // 128x128 bf16, swizzled
    char* wsh = lds + 32768;    // WT 128x128 bf16 ([n][k]), swizzled
    int t = threadIdx.x;
    int base = blockIdx.x * 128;

    #pragma unroll
    for (int j = 0; j < 8; ++j) {
        int idx = j * 256 + t;
        int n = idx >> 4, c8 = idx & 15;
        short8 v = *(const short8*)(WT + n * 128 + c8 * 8);
        int off = (n * 256 + c8 * 16) ^ ((n & 7) << 4);
        *(short8*)(wsh + off) = v;
    }
    #pragma unroll
    for (int j = 0; j < 8; ++j) {
        int idx = j * 256 + t;
        int row = idx >> 4, c8 = idx & 15;
        int grow = base + row;
        short8 v = {0,0,0,0,0,0,0,0};
        if (grow < nrows) {
            if (IN_F32) {
                const float* Xf = (const float*)Xv;
                float4 a = *(const float4*)(Xf + (size_t)grow * 128 + c8 * 8);
                float4 b = *(const float4*)(Xf + (size_t)grow * 128 + c8 * 8 + 4);
                v[0] = (short)f2bf(a.x); v[1] = (short)f2bf(a.y);
                v[2] = (short)f2bf(a.z); v[3] = (short)f2bf(a.w);
                v[4] = (short)f2bf(b.x); v[5] = (short)f2bf(b.y);
                v[6] = (short)f2bf(b.z); v[7] = (short)f2bf(b.w);
            } else {
                // chunk-major: features [c8*8, c8*8+8) = chunk c8>>1, half c8&1
                const unsigned short* Xb = (const unsigned short*)Xv;
                v = *(const short8*)(Xb + (size_t)(c8 >> 1) * CHS + (size_t)grow * 16 + (c8 & 1) * 8);
            }
        }
        int off = (row * 256 + c8 * 16) ^ ((row & 7) << 4);
        *(short8*)(xs + off) = v;
    }
    __syncthreads();

    int lane = t & 63, w = t >> 6;
    int lhi = lane >> 4, llo = lane & 15;
    f32x4 acc[2][8];
    #pragma unroll
    for (int r = 0; r < 2; ++r)
        #pragma unroll
        for (int c = 0; c < 8; ++c) acc[r][c] = (f32x4){0.f, 0.f, 0.f, 0.f};

    #pragma unroll
    for (int kk = 0; kk < 4; ++kk) {
        short8 a[2];
        #pragma unroll
        for (int r = 0; r < 2; ++r) {
            int row = w * 32 + r * 16 + llo;
            int off = (row * 256 + kk * 64 + lhi * 16) ^ ((row & 7) << 4);
            a[r] = *(const short8*)(xs + off);
        }
        #pragma unroll
        for (int c = 0; c < 8; ++c) {
            int col = c * 16 + llo;
            int off = (col * 256 + kk * 64 + lhi * 16) ^ ((col & 7) << 4);
            short8 bb = *(const short8*)(wsh + off);
            acc[0][c] = __builtin_amdgcn_mfma_f32_16x16x32_bf16(a[0], bb, acc[0][c], 0, 0, 0);
            acc[1][c] = __builtin_amdgcn_mfma_f32_16x16x32_bf16(a[1], bb, acc[1][c], 0, 0, 0);
        }
    }

    // D: col = c*16 + llo -> chunk c, offset llo (chunk-major store)
    #pragma unroll
    for (int r = 0; r < 2; ++r) {
        #pragma unroll
        for (int reg = 0; reg < 4; ++reg) {
            int grow = base + w * 32 + r * 16 + lhi * 4 + reg;
            if (grow < nrows) {
                #pragma unroll
                for (int c = 0; c < 8; ++c)
                    H[(size_t)c * CHS + (size_t)grow * 16 + llo] = f2bf(acc[r][c][reg]);
            }
        }
    }
}

// ---------------- aggregation, chunk-major + XCD-affine ----------------
// chunk cm = blockIdx % 8 -> XCD cm (round-robin dispatch). Block: 16 nodes x 16 lanes each.
// lane-in-16: slot=(l>>1)&7 (8 edge slots), h=l&1 (feature half). 2-way unroll: 16 edges in flight.
__global__ __launch_bounds__(256) void agg_bf16(const unsigned short* __restrict__ H,
                                                unsigned short* __restrict__ O,
                                                const float* __restrict__ dinv,
                                                const int* __restrict__ row_ptr,
                                                const int* __restrict__ esrc,
                                                const float* __restrict__ bias) {
    int cm  = blockIdx.x & 7;
    int grp = blockIdx.x >> 3;
    int t = threadIdx.x;
    int node = grp * 16 + (t >> 4);
    int slot = (t >> 1) & 7;
    int h    = t & 1;
    const unsigned short* Hc = H + (size_t)cm * CHS;

    float dv = dinv[node];
    float acc[8];
    #pragma unroll
    for (int j = 0; j < 8; ++j) acc[j] = 0.f;

    int beg = row_ptr[node], end = row_ptr[node + 1];   // includes self edge (>=1 slot)
    for (int e0 = beg; e0 < end; e0 += 16) {
        int ea = e0 + slot;
        int eb = ea + 8;
        int ca = min(ea, end - 1);
        int cb = min(eb, end - 1);
        int s0 = esrc[ca];
        int s1 = esrc[cb];
        float w0 = (ea < end) ? dinv[s0] * dv : 0.f;
        float w1 = (eb < end) ? dinv[s1] * dv : 0.f;
        short8 m0 = *(const short8*)(Hc + (size_t)s0 * 16 + h * 8);
        short8 m1 = *(const short8*)(Hc + (size_t)s1 * 16 + h * 8);
        #pragma unroll
        for (int j = 0; j < 8; ++j) acc[j] += bf2f((unsigned short)m0[j]) * w0;
        #pragma unroll
        for (int j = 0; j < 8; ++j) acc[j] += bf2f((unsigned short)m1[j]) * w1;
    }

    // reduce across 8 slots (lane strides 2,4,8 within 16-lane node group)
    #pragma unroll
    for (int j = 0; j < 8; ++j) {
        acc[j] += __shfl_xor(acc[j], 2, 64);
        acc[j] += __shfl_xor(acc[j], 4, 64);
        acc[j] += __shfl_xor(acc[j], 8, 64);
    }

    if (slot == 0) {
        int fb = cm * 16 + h * 8;
        float4 b0 = *(const float4*)(bias + fb);
        float4 b1 = *(const float4*)(bias + fb + 4);
        short8 v;
        v[0] = (short)f2bf(fmaxf(acc[0] + b0.x, 0.f));
        v[1] = (short)f2bf(fmaxf(acc[1] + b0.y, 0.f));
        v[2] = (short)f2bf(fmaxf(acc[2] + b0.z, 0.f));
        v[3] = (short)f2bf(fmaxf(acc[3] + b0.w, 0.f));
        v[4] = (short)f2bf(fmaxf(acc[4] + b1.x, 0.f));
        v[5] = (short)f2bf(fmaxf(acc[5] + b1.y, 0.f));
        v[6] = (short)f2bf(fmaxf(acc[6] + b1.z, 0.f));
        v[7] = (short)f2bf(fmaxf(acc[7] + b1.w, 0.f));
        *(short8*)(O + (size_t)cm * CHS + (size_t)node * 16 + h * 8) = v;
    }
}

// ---------------- pooling (chunk-major bf16 input) ----------------
__global__ __launch_bounds__(128) void pool_kernel(const unsigned short* __restrict__ H, const int* __restrict__ batch,
                                                   float* __restrict__ pooled, float* __restrict__ cnt) {
    int f  = threadIdx.x;
    size_t faddr = (size_t)(f >> 4) * CHS + (f & 15);
    int r0 = blockIdx.x * 128;
    int rend = r0 + 128; if (rend > N_NODES) rend = N_NODES;
    if (r0 >= N_NODES) return;
    float acc = 0.f;
    int g_cur = batch[r0];
    int run = 0;
    for (int r = r0; r < rend; ++r) {
        int g = batch[r];
        if (g != g_cur) {
            atomicAdd(&pooled[g_cur * FDIM + f], acc);
            if (f == 0) atomicAdd(&cnt[g_cur], (float)run);
            acc = 0.f; run = 0; g_cur = g;
        }
        acc += bf2f(H[faddr + (size_t)r * 16]);
        run++;
    }
    atomicAdd(&pooled[g_cur * FDIM + f], acc);
    if (f == 0) atomicAdd(&cnt[g_cur], (float)run);
}

// ---------------- final FC ----------------
__global__ __launch_bounds__(256) void fc_kernel(const float* __restrict__ pooled, const float* __restrict__ cnt,
                                                 const float* __restrict__ fcW, const float* __restrict__ fcb,
                                                 float* __restrict__ out) {
    int idx = blockIdx.x * 256 + threadIdx.x;
    if (idx >= N_GRAPHS * N_CLASSES) return;
    int g = idx >> 5, c = idx & 31;
    float inv = 1.0f / fmaxf(cnt[g], 1.0f);
    float acc = 0.f;
    #pragma unroll 16
    for (int k = 0; k < FDIM; ++k) acc += pooled[g * FDIM + k] * fcW[k * N_CLASSES + c];
    out[idx] = acc * inv + fcb[c];
}

extern "C" void kernel_launch(void* const* d_in, const int* in_sizes, int n_in,
                              void* d_out, int out_size, void* d_ws, size_t ws_size,
                              hipStream_t stream) {
    const float* x    = (const float*)d_in[0];
    const int*   ei   = (const int*)d_in[1];     // [2, E] int32
    const int*   batch= (const int*)d_in[2];
    const float* W1   = (const float*)d_in[3];
    const float* b1   = (const float*)d_in[4];
    const float* W2   = (const float*)d_in[5];
    const float* b2   = (const float*)d_in[6];
    const float* fcW  = (const float*)d_in[7];
    const float* fcb  = (const float*)d_in[8];
    float* out = (float*)d_out;

    const int nE = in_sizes[1] / 2;
    const int* src = ei;
    const int* dst = ei + nE;

    const int nblk  = (nE + EPB - 1) / EPB;
    const int histN = NB * nblk;
    const int sB    = (histN + SCAN_CHUNK - 1) / SCAN_CHUNK;
    const int nSlots = nE + N_NODES;             // edges + self edges

    // workspace layout
    unsigned short* Hb0 = (unsigned short*)d_ws;                 // 8*N*16 bf16 (chunk-major)
    unsigned short* Hb1 = Hb0 + (size_t)N_NODES * FDIM;          // 8*N*16 bf16
    unsigned short* W1T = Hb1 + (size_t)N_NODES * FDIM;          // 128*128 bf16
    unsigned short* W2T = W1T + FDIM * FDIM;                     // 128*128 bf16
    float* dinv    = (float*)(W2T + FDIM * FDIM);                // N
    int*   row_ptr = (int*)(dinv + N_NODES);                     // N+1
    int*   esrc    = row_ptr + N_NODES + 1;                      // nE + N
    unsigned long long* recs = (unsigned long long*)(esrc + ((nSlots + 1) & ~1)); // nE (8B aligned)
    int*   hist    = (int*)(recs + nE);                          // NB*nblk
    int*   bsums   = hist + histN;                               // sB
    float* pooled  = (float*)(bsums + ((sB + 1) & ~1));          // G*F
    float* cnt     = pooled + N_GRAPHS * FDIM;                   // G

    hipMemsetAsync(pooled, 0, (N_GRAPHS * FDIM + N_GRAPHS) * sizeof(float), stream);

    wtrans<<<64, 256, 0, stream>>>(W1, W1T);
    wtrans<<<64, 256, 0, stream>>>(W2, W2T);

    // CSR build: hist -> scan -> partition -> per-bucket CSR (+self edges, dinv)
    hist_kernel<<<nblk, 256, 0, stream>>>(dst, hist, nE, nblk);
    scan_p1<<<sB, 256, 0, stream>>>(hist, bsums, histN);
    scan_p2<<<1, 64, 0, stream>>>(bsums, sB);
    scan_p3<<<sB, 256, 0, stream>>>(hist, bsums, hist, histN);
    part_kernel<<<nblk, 256, 0, stream>>>(src, dst, hist, recs, nE, nblk);
    csr_kernel<<<NB, 256, 0, stream>>>(recs, hist, row_ptr, esrc, dinv, nE, nblk);

    const int gemm_grid = (N_NODES + 127) / 128;
    const int agg_grid  = (N_NODES / 16) * 8;     // 6250 groups x 8 chunks
    // layer 1
    gemm_mfma<1><<<gemm_grid, 256, 0, stream>>>(x, W1T, Hb0, N_NODES);
    agg_bf16<<<agg_grid, 256, 0, stream>>>(Hb0, Hb1, dinv, row_ptr, esrc, b1);
    // layer 2
    gemm_mfma<0><<<gemm_grid, 256, 0, stream>>>(Hb1, W2T, Hb0, N_NODES);
    agg_bf16<<<agg_grid, 256, 0, stream>>>(Hb0, Hb1, dinv, row_ptr, esrc, b2);

    // pool + fc
    pool_kernel<<<(N_NODES + 127) / 128, 128, 0, stream>>>(Hb1, batch, pooled, cnt);
    fc_kernel<<<(N_GRAPHS * N_CLASSES + 255) / 256, 256, 0, stream>>>(pooled, cnt, fcW, fcb, out);
}

// Round 12
// 385.540 us; speedup vs baseline: 1.2459x; 1.2459x over previous
//
#include <hip/hip_runtime.h>
#include <hip/hip_bf16.h>

#define N_NODES   100000
#define FDIM      128
#define N_GRAPHS  64
#define N_CLASSES 32

#define NB        ((N_NODES + 255) / 256)     // 391 buckets of 256 nodes
#define EPB       8192                         // edges per block (hist/part)
#define SCAN_CHUNK 2048

typedef __attribute__((ext_vector_type(8))) short short8;
typedef __attribute__((ext_vector_type(4))) float f32x4;

__device__ __forceinline__ float bf2f(unsigned int u16) {
    unsigned int x = u16 << 16;
    return __builtin_bit_cast(float, x);
}
__device__ __forceinline__ unsigned short f2bf(float f) {
    unsigned int u = __builtin_bit_cast(unsigned int, f);
    unsigned int r = (u + 0x7fffu + ((u >> 16) & 1u)) >> 16;   // RNE
    return (unsigned short)r;
}

// ---------------- bucket histogram: hist[bucket * nblk + blk] ----------------
__global__ __launch_bounds__(256) void hist_kernel(const int* __restrict__ dst, int* __restrict__ hist,
                                                   int nE, int nblk) {
    __shared__ int h[NB];
    int t = threadIdx.x, blk = blockIdx.x;
    for (int i = t; i < NB; i += 256) h[i] = 0;
    __syncthreads();
    int base = blk * EPB;
    #pragma unroll
    for (int j = 0; j < EPB / 256; ++j) {
        int e = base + j * 256 + t;
        if (e < nE) atomicAdd(&h[dst[e] >> 8], 1);
    }
    __syncthreads();
    for (int i = t; i < NB; i += 256) hist[i * nblk + blk] = h[i];
}

// ---------------- generic two-level exclusive scan ----------------
__global__ __launch_bounds__(256) void scan_p1(const int* __restrict__ a, int* __restrict__ bsums, int n) {
    __shared__ int wsum[4];
    int b = blockIdx.x, t = threadIdx.x;
    int base = b * SCAN_CHUNK;
    int sum = 0;
    #pragma unroll
    for (int j = 0; j < SCAN_CHUNK / 256; ++j) {
        int idx = base + j * 256 + t;
        sum += (idx < n) ? a[idx] : 0;
    }
    #pragma unroll
    for (int off = 32; off; off >>= 1) sum += __shfl_down(sum, off, 64);
    int lane = t & 63, w = t >> 6;
    if (lane == 0) wsum[w] = sum;
    __syncthreads();
    if (t == 0) bsums[b] = wsum[0] + wsum[1] + wsum[2] + wsum[3];
}

__global__ __launch_bounds__(64) void scan_p2(int* __restrict__ bsums, int nb) {
    int t = threadIdx.x;
    int carry = 0;
    for (int base = 0; base < nb; base += 64) {
        int i = base + t;
        int v = (i < nb) ? bsums[i] : 0;
        int inc = v;
        #pragma unroll
        for (int off = 1; off < 64; off <<= 1) {
            int y = __shfl_up(inc, off, 64);
            if (t >= off) inc += y;
        }
        if (i < nb) bsums[i] = carry + inc - v;   // exclusive
        carry += __shfl(inc, 63, 64);
    }
}

__global__ __launch_bounds__(256) void scan_p3(const int* __restrict__ a, const int* __restrict__ bsums,
                                               int* __restrict__ out, int n) {
    __shared__ int wsum[4];
    int b = blockIdx.x, t = threadIdx.x;
    int lane = t & 63, w = t >> 6;
    int i0 = b * SCAN_CHUNK + t * 8;
    int v[8];
    int s = 0;
    #pragma unroll
    for (int j = 0; j < 8; ++j) {
        int idx = i0 + j;
        v[j] = (idx < n) ? a[idx] : 0;
        s += v[j];
    }
    int ps = s;
    #pragma unroll
    for (int off = 1; off < 64; off <<= 1) {
        int y = __shfl_up(ps, off, 64);
        if (lane >= off) ps += y;
    }
    if (lane == 63) wsum[w] = ps;
    __syncthreads();
    if (t == 0) {
        int acc = 0;
        #pragma unroll
        for (int i = 0; i < 4; ++i) { int tmp = wsum[i]; wsum[i] = acc; acc += tmp; }
    }
    __syncthreads();
    int run = (ps - s) + wsum[w] + bsums[b];
    #pragma unroll
    for (int j = 0; j < 8; ++j) {
        int idx = i0 + j;
        if (idx < n) out[idx] = run;
        run += v[j];
    }
}

// ---------------- partition edges into bucket-major record array ----------------
__global__ __launch_bounds__(256) void part_kernel(const int* __restrict__ src, const int* __restrict__ dst,
                                                   const int* __restrict__ offs,
                                                   unsigned long long* __restrict__ recs,
                                                   int nE, int nblk) {
    __shared__ int cur[NB];
    int t = threadIdx.x, blk = blockIdx.x;
    for (int i = t; i < NB; i += 256) cur[i] = offs[i * nblk + blk];
    __syncthreads();
    int base = blk * EPB;
    #pragma unroll
    for (int j = 0; j < EPB / 256; ++j) {
        int e = base + j * 256 + t;
        if (e < nE) {
            int s = src[e], d = dst[e];
            int pos = atomicAdd(&cur[d >> 8], 1);
            recs[pos] = (unsigned long long)(unsigned)s | ((unsigned long long)(unsigned)d << 32);
        }
    }
}

// ---------------- per-bucket CSR build WITH self-edges: row = [self | edges] ----------------
__global__ __launch_bounds__(256) void csr_kernel(const unsigned long long* __restrict__ recs,
                                                  const int* __restrict__ offs,
                                                  int* __restrict__ row_ptr, int* __restrict__ esrc,
                                                  float* __restrict__ dinv, int nE, int nblk) {
    __shared__ int cnt[256];
    __shared__ int cur[256];
    __shared__ int wsum[4];
    int b = blockIdx.x, t = threadIdx.x;
    int node0 = b << 8;
    int segBeg = offs[b * nblk];
    int segEnd = (b + 1 < NB) ? offs[(b + 1) * nblk] : nE;
    cnt[t] = 0;
    __syncthreads();
    for (int e = segBeg + t; e < segEnd; e += 256) {
        int d = (int)(recs[e] >> 32);
        atomicAdd(&cnt[d - node0], 1);
    }
    __syncthreads();
    int c = cnt[t];
    int lane = t & 63, w = t >> 6;
    int ps = c;
    #pragma unroll
    for (int off = 1; off < 64; off <<= 1) {
        int y = __shfl_up(ps, off, 64);
        if (lane >= off) ps += y;
    }
    if (lane == 63) wsum[w] = ps;
    __syncthreads();
    if (t == 0) {
        int a = 0;
        #pragma unroll
        for (int i = 0; i < 4; ++i) { int tmp = wsum[i]; wsum[i] = a; a += tmp; }
    }
    __syncthreads();
    int node = node0 + t;
    int rbase = segBeg + node0 + (ps - c) + wsum[w] + t;   // includes self slots of prior nodes
    if (node < N_NODES) {
        row_ptr[node] = rbase;
        esrc[rbase] = node;            // self edge first
        dinv[node] = rsqrtf((float)c + 1.0f);
        cur[t] = rbase + 1;
    } else {
        cur[t] = 0;
    }
    if (b == NB - 1 && t == 0) row_ptr[N_NODES] = nE + N_NODES;
    __syncthreads();
    for (int e = segBeg + t; e < segEnd; e += 256) {
        unsigned long long r = recs[e];
        int d = (int)(r >> 32);
        int pos = atomicAdd(&cur[d - node0], 1);
        esrc[pos] = (int)(r & 0xffffffffu);
    }
}

// ---------------- W transpose + cast (both weights, one launch) ----------------
__global__ __launch_bounds__(256) void wtrans2(const float* __restrict__ W1, const float* __restrict__ W2,
                                               unsigned short* __restrict__ W1T, unsigned short* __restrict__ W2T) {
    int idx = blockIdx.x * 256 + threadIdx.x;
    const float* W = (idx < 16384) ? W1 : W2;
    unsigned short* WT = (idx < 16384) ? W1T : W2T;
    int i = idx & 16383;
    int k = i >> 7, n = i & 127;
    WT[n * 128 + k] = f2bf(W[i]);
}

// ---------------- MFMA GEMM: H[nrows x 128](bf16, row-major) = X @ W ----------------
// LDS-staged vectorized epilogue (1KB-contiguous short8 stores).
template<int IN_F32>
__global__ __launch_bounds__(256) void gemm_mfma(const void* __restrict__ Xv,
                                                 const unsigned short* __restrict__ WT,
                                                 unsigned short* __restrict__ H, int nrows) {
    __shared__ char lds[65536];
    char* xs  = lds;            // 128x128 bf16, swizzled (reused for C-tile staging)
    char* wsh = lds + 32768;    // WT 128x128 bf16 ([n][k]), swizzled
    int t = threadIdx.x;
    int base = blockIdx.x * 128;

    #pragma unroll
    for (int j = 0; j < 8; ++j) {
        int idx = j * 256 + t;
        int n = idx >> 4, c8 = idx & 15;
        short8 v = *(const short8*)(WT + n * 128 + c8 * 8);
        int off = (n * 256 + c8 * 16) ^ ((n & 7) << 4);
        *(short8*)(wsh + off) = v;
    }
    #pragma unroll
    for (int j = 0; j < 8; ++j) {
        int idx = j * 256 + t;
        int row = idx >> 4, c8 = idx & 15;
        int grow = base + row;
        short8 v = {0,0,0,0,0,0,0,0};
        if (grow < nrows) {
            if (IN_F32) {
                const float* Xf = (const float*)Xv;
                float4 a = *(const float4*)(Xf + (size_t)grow * 128 + c8 * 8);
                float4 b = *(const float4*)(Xf + (size_t)grow * 128 + c8 * 8 + 4);
                v[0] = (short)f2bf(a.x); v[1] = (short)f2bf(a.y);
                v[2] = (short)f2bf(a.z); v[3] = (short)f2bf(a.w);
                v[4] = (short)f2bf(b.x); v[5] = (short)f2bf(b.y);
                v[6] = (short)f2bf(b.z); v[7] = (short)f2bf(b.w);
            } else {
                const unsigned short* Xb = (const unsigned short*)Xv;
                v = *(const short8*)(Xb + (size_t)grow * 128 + c8 * 8);
            }
        }
        int off = (row * 256 + c8 * 16) ^ ((row & 7) << 4);
        *(short8*)(xs + off) = v;
    }
    __syncthreads();

    int lane = t & 63, w = t >> 6;
    int lhi = lane >> 4, llo = lane & 15;
    f32x4 acc[2][8];
    #pragma unroll
    for (int r = 0; r < 2; ++r)
        #pragma unroll
        for (int c = 0; c < 8; ++c) acc[r][c] = (f32x4){0.f, 0.f, 0.f, 0.f};

    #pragma unroll
    for (int kk = 0; kk < 4; ++kk) {
        short8 a[2];
        #pragma unroll
        for (int r = 0; r < 2; ++r) {
            int row = w * 32 + r * 16 + llo;
            int off = (row * 256 + kk * 64 + lhi * 16) ^ ((row & 7) << 4);
            a[r] = *(const short8*)(xs + off);
        }
        #pragma unroll
        for (int c = 0; c < 8; ++c) {
            int col = c * 16 + llo;
            int off = (col * 256 + kk * 64 + lhi * 16) ^ ((col & 7) << 4);
            short8 bb = *(const short8*)(wsh + off);
            acc[0][c] = __builtin_amdgcn_mfma_f32_16x16x32_bf16(a[0], bb, acc[0][c], 0, 0, 0);
            acc[1][c] = __builtin_amdgcn_mfma_f32_16x16x32_bf16(a[1], bb, acc[1][c], 0, 0, 0);
        }
    }

    // stage C tile (row-major bf16 128x128) into LDS, then vector stores
    __syncthreads();
    unsigned short* ct = (unsigned short*)lds;
    #pragma unroll
    for (int r = 0; r < 2; ++r) {
        #pragma unroll
        for (int reg = 0; reg < 4; ++reg) {
            int row = w * 32 + r * 16 + lhi * 4 + reg;
            #pragma unroll
            for (int c = 0; c < 8; ++c)
                ct[row * 128 + c * 16 + llo] = f2bf(acc[r][c][reg]);
        }
    }
    __syncthreads();
    #pragma unroll
    for (int k = 0; k < 8; ++k) {
        int elem = w * 4096 + k * 512 + lane * 8;     // 1KB contiguous per instruction
        int row = elem >> 7, col = elem & 127;
        if (base + row < nrows)
            *(short8*)(H + (size_t)(base + row) * 128 + col) = *(const short8*)(ct + elem);
    }
}

// ---------------- aggregation (bf16, row-major): 4 edge-slots x 16 lanes, x4 unroll ----------------
// LAYER 0: compute w_e = dinv[src]*dinv[dst], store to wbuf. LAYER 1: stream wbuf (no random dinv gather).
// CSR includes self edge, so acc starts at 0 and loop is uniform.
template<int LAYER>
__global__ __launch_bounds__(256) void agg_bf16(const unsigned short* __restrict__ H,
                                                unsigned short* __restrict__ O,
                                                const float* __restrict__ dinv,
                                                const int* __restrict__ row_ptr,
                                                const int* __restrict__ esrc,
                                                float* __restrict__ wbuf,
                                                const float* __restrict__ bias) {
    int node = blockIdx.x * 4 + (threadIdx.x >> 6);
    if (node >= N_NODES) return;
    int lane = threadIdx.x & 63;
    int g  = lane >> 4;        // edge slot 0..3
    int fl = lane & 15;        // feature chunk: features [fl*8, fl*8+8)

    float dv = dinv[node];
    float acc[8];
    #pragma unroll
    for (int j = 0; j < 8; ++j) acc[j] = 0.f;

    int beg = row_ptr[node], end = row_ptr[node + 1];   // includes self edge
    for (int e0 = beg; e0 < end; e0 += 16) {
        int eb = e0 + g * 4;
        int s[4];
        float wg[4];
        #pragma unroll
        for (int u = 0; u < 4; ++u) {
            int e = eb + u;
            int ee = min(e, end - 1);           // clamp: tail lanes re-read a hot slot
            s[u] = esrc[ee];
            bool val = e < end;
            if (LAYER == 0) {
                float wv = dinv[s[u]] * dv;
                wg[u] = val ? wv : 0.f;
                if (val && fl == 0) wbuf[e] = wv;
            } else {
                wg[u] = val ? wbuf[ee] : 0.f;
            }
        }
        #pragma unroll
        for (int u = 0; u < 4; ++u) {
            short8 m = *(const short8*)(H + (size_t)s[u] * FDIM + fl * 8);
            float wgt = wg[u];
            #pragma unroll
            for (int j = 0; j < 8; ++j) acc[j] += bf2f((unsigned short)m[j]) * wgt;
        }
    }

    // reduce across the 4 edge slots
    #pragma unroll
    for (int j = 0; j < 8; ++j) {
        acc[j] += __shfl_xor(acc[j], 16, 64);
        acc[j] += __shfl_xor(acc[j], 32, 64);
    }

    float4 b0 = *(const float4*)(bias + fl * 8);
    float4 b1 = *(const float4*)(bias + fl * 8 + 4);
    float r0 = fmaxf(acc[0] + b0.x, 0.f), r1 = fmaxf(acc[1] + b0.y, 0.f);
    float r2 = fmaxf(acc[2] + b0.z, 0.f), r3 = fmaxf(acc[3] + b0.w, 0.f);
    float r4 = fmaxf(acc[4] + b1.x, 0.f), r5 = fmaxf(acc[5] + b1.y, 0.f);
    float r6 = fmaxf(acc[6] + b1.z, 0.f), r7 = fmaxf(acc[7] + b1.w, 0.f);
    if (g == 0) {
        short8 v;
        v[0] = (short)f2bf(r0); v[1] = (short)f2bf(r1);
        v[2] = (short)f2bf(r2); v[3] = (short)f2bf(r3);
        v[4] = (short)f2bf(r4); v[5] = (short)f2bf(r5);
        v[6] = (short)f2bf(r6); v[7] = (short)f2bf(r7);
        *(short8*)(O + (size_t)node * FDIM + fl * 8) = v;
    }
}

// ---------------- pooling (bf16 input, row-major) ----------------
__global__ __launch_bounds__(128) void pool_kernel(const unsigned short* __restrict__ H, const int* __restrict__ batch,
                                                   float* __restrict__ pooled, float* __restrict__ cnt) {
    int f  = threadIdx.x;
    int r0 = blockIdx.x * 128;
    int rend = r0 + 128; if (rend > N_NODES) rend = N_NODES;
    if (r0 >= N_NODES) return;
    float acc = 0.f;
    int g_cur = batch[r0];
    int run = 0;
    for (int r = r0; r < rend; ++r) {
        int g = batch[r];
        if (g != g_cur) {
            atomicAdd(&pooled[g_cur * FDIM + f], acc);
            if (f == 0) atomicAdd(&cnt[g_cur], (float)run);
            acc = 0.f; run = 0; g_cur = g;
        }
        acc += bf2f(H[(size_t)r * FDIM + f]);
        run++;
    }
    atomicAdd(&pooled[g_cur * FDIM + f], acc);
    if (f == 0) atomicAdd(&cnt[g_cur], (float)run);
}

// ---------------- final FC ----------------
__global__ __launch_bounds__(256) void fc_kernel(const float* __restrict__ pooled, const float* __restrict__ cnt,
                                                 const float* __restrict__ fcW, const float* __restrict__ fcb,
                                                 float* __restrict__ out) {
    int idx = blockIdx.x * 256 + threadIdx.x;
    if (idx >= N_GRAPHS * N_CLASSES) return;
    int g = idx >> 5, c = idx & 31;
    float inv = 1.0f / fmaxf(cnt[g], 1.0f);
    float acc = 0.f;
    #pragma unroll 16
    for (int k = 0; k < FDIM; ++k) acc += pooled[g * FDIM + k] * fcW[k * N_CLASSES + c];
    out[idx] = acc * inv + fcb[c];
}

extern "C" void kernel_launch(void* const* d_in, const int* in_sizes, int n_in,
                              void* d_out, int out_size, void* d_ws, size_t ws_size,
                              hipStream_t stream) {
    const float* x    = (const float*)d_in[0];
    const int*   ei   = (const int*)d_in[1];     // [2, E] int32
    const int*   batch= (const int*)d_in[2];
    const float* W1   = (const float*)d_in[3];
    const float* b1   = (const float*)d_in[4];
    const float* W2   = (const float*)d_in[5];
    const float* b2   = (const float*)d_in[6];
    const float* fcW  = (const float*)d_in[7];
    const float* fcb  = (const float*)d_in[8];
    float* out = (float*)d_out;

    const int nE = in_sizes[1] / 2;
    const int* src = ei;
    const int* dst = ei + nE;

    const int nblk  = (nE + EPB - 1) / EPB;
    const int histN = NB * nblk;
    const int sB    = (histN + SCAN_CHUNK - 1) / SCAN_CHUNK;
    const int nSlots = nE + N_NODES;             // edges + self edges

    // workspace layout
    unsigned short* Hb0 = (unsigned short*)d_ws;                 // N*128 bf16 (row-major)
    unsigned short* Hb1 = Hb0 + (size_t)N_NODES * FDIM;          // N*128 bf16
    unsigned short* W1T = Hb1 + (size_t)N_NODES * FDIM;          // 128*128 bf16
    unsigned short* W2T = W1T + FDIM * FDIM;                     // 128*128 bf16
    float* dinv    = (float*)(W2T + FDIM * FDIM);                // N
    int*   row_ptr = (int*)(dinv + N_NODES);                     // N+1
    int*   esrc    = row_ptr + N_NODES + 1;                      // nE + N
    float* wbuf    = (float*)(esrc + nSlots);                    // nE + N
    unsigned long long* recs = (unsigned long long*)
        ((char*)(wbuf + nSlots) + (((size_t)(wbuf + nSlots)) & 4 ? 4 : 0)); // 8B align
    int*   hist    = (int*)(recs + nE);                          // NB*nblk
    int*   bsums   = hist + histN;                               // sB
    float* pooled  = (float*)(bsums + ((sB + 1) & ~1));          // G*F
    float* cnt     = pooled + N_GRAPHS * FDIM;                   // G

    hipMemsetAsync(pooled, 0, (N_GRAPHS * FDIM + N_GRAPHS) * sizeof(float), stream);

    wtrans2<<<128, 256, 0, stream>>>(W1, W2, W1T, W2T);

    // CSR build: hist -> scan -> partition -> per-bucket CSR (+self edges, dinv)
    hist_kernel<<<nblk, 256, 0, stream>>>(dst, hist, nE, nblk);
    scan_p1<<<sB, 256, 0, stream>>>(hist, bsums, histN);
    scan_p2<<<1, 64, 0, stream>>>(bsums, sB);
    scan_p3<<<sB, 256, 0, stream>>>(hist, bsums, hist, histN);
    part_kernel<<<nblk, 256, 0, stream>>>(src, dst, hist, recs, nE, nblk);
    csr_kernel<<<NB, 256, 0, stream>>>(recs, hist, row_ptr, esrc, dinv, nE, nblk);

    const int gemm_grid = (N_NODES + 127) / 128;
    // layer 1
    gemm_mfma<1><<<gemm_grid, 256, 0, stream>>>(x, W1T, Hb0, N_NODES);
    agg_bf16<0><<<(N_NODES + 3) / 4, 256, 0, stream>>>(Hb0, Hb1, dinv, row_ptr, esrc, wbuf, b1);
    // layer 2
    gemm_mfma<0><<<gemm_grid, 256, 0, stream>>>(Hb1, W2T, Hb0, N_NODES);
    agg_bf16<1><<<(N_NODES + 3) / 4, 256, 0, stream>>>(Hb0, Hb1, dinv, row_ptr, esrc, wbuf, b2);

    // pool + fc
    pool_kernel<<<(N_NODES + 127) / 128, 128, 0, stream>>>(Hb1, batch, pooled, cnt);
    fc_kernel<<<(N_GRAPHS * N_CLASSES + 255) / 256, 256, 0, stream>>>(pooled, cnt, fcW, fcb, out);
}